// Round 10
// baseline (293.616 us; speedup 1.0000x reference)
//
#include <hip/hip_runtime.h>
#include <stdint.h>

// ---------------------------------------------------------------------------
// UserSpotConv: bipartite GCN aggregation.
//   user_out[u] = isd_u[u] * sum_{e: u_e=u} spot_x[s_e] * isd_s[s_e]
//   spot_out[s] = isd_s[s] * sum_{e: s_e=s} user_x[u_e] * isd_u[u_e]
// Round 10: the gather needs BOTH >=7K waves (r8 lesson) AND a single table
// resident (r9 lesson). fscan3 = per-direction launch, each bucket split
// into `split` sub-blocks (u: 1696 blocks/13.5K waves; s: 2010 blocks):
// sub-block reads its ~1.2K edges once into regs, LDS ushort counting-sort
// (8.5 KB -> 4 blocks/CU), dst-major register accumulate, atomic flush
// (sub-blocks share rows). isd via bdeg2. Shared pipeline: part2 fuses both
// directions (edges read once), convert2 fuses both table converts.
// ---------------------------------------------------------------------------

#define NPB_LOG2 6
#define NPB 64             // destination nodes per bucket
#define MAXB 768           // max buckets per direction
#define PART_CHUNK 2048    // edges per block in part2_kernel
#define BH_CHUNK 16384     // edges per block in bhist_kernel
#define SORT_CAP 8192      // tier-B fscan: max edges per bucket (u32 stage)
#define RCAP 4096          // fscan3: max edges per sub-block (ushort stage)

__device__ __forceinline__ ushort f2bf(float f) {
    uint32_t u = __float_as_uint(f);
    return (ushort)((u + 0x7fffu + ((u >> 16) & 1u)) >> 16);  // RNE
}

// Bucket-level histogram for BOTH directions in one pass.
__global__ __launch_bounds__(256) void bhist_kernel(
        const int* __restrict__ u, const int* __restrict__ s, int E,
        int nbu, int nbs, int* __restrict__ bd) {
    __shared__ int hist[2 * MAXB];
    const int tid = threadIdx.x;
    const int nb = nbu + nbs;
    const int beg = blockIdx.x * BH_CHUNK;
    const int end = min(beg + BH_CHUNK, E);
    for (int b = tid; b < nb; b += 256) hist[b] = 0;
    __syncthreads();
    for (int i = beg + tid; i < end; i += 256) {
        atomicAdd(&hist[u[i] >> NPB_LOG2], 1);
        atomicAdd(&hist[nbu + (s[i] >> NPB_LOG2)], 1);
    }
    __syncthreads();
    for (int b = tid; b < nb; b += 256) {
        int h = hist[b];
        if (h) atomicAdd(&bd[b], h);
    }
}

// Fused dual exclusive scan (block 0: u-buckets, block 1: s-buckets) that
// also initializes the part2 global cursors. n <= 1024 (MAXB=768).
__global__ __launch_bounds__(1024) void scan2_kernel(
        const int* __restrict__ bd, int nbu, int nbs,
        int* __restrict__ buoff, int* __restrict__ bsoff,
        int* __restrict__ gcu, int* __restrict__ gcs) {
    __shared__ int wsums[16];
    __shared__ int total;
    const int tid = threadIdx.x, lane = tid & 63, wid = tid >> 6;
    const int n   = blockIdx.x ? nbs : nbu;
    const int* in = blockIdx.x ? (bd + nbu) : bd;
    int* out = blockIdx.x ? bsoff : buoff;
    int* gc  = blockIdx.x ? gcs   : gcu;
    int v = (tid < n) ? in[tid] : 0;
    int x = v;
#pragma unroll
    for (int d = 1; d < 64; d <<= 1) {
        int t = __shfl_up(x, d);
        if (lane >= d) x += t;
    }
    if (lane == 63) wsums[wid] = x;
    __syncthreads();
    if (tid == 0) {
        int run = 0;
#pragma unroll
        for (int w = 0; w < 16; ++w) { int t = wsums[w]; wsums[w] = run; run += t; }
        total = run;
    }
    __syncthreads();
    int excl = wsums[wid] + (x - v);
    if (tid < n) { out[tid] = excl; gc[tid] = excl; }
    if (tid == 0) out[n] = total;
}

// xb row layout is PERMUTED: slot 2c holds col c, slot 2c+1 holds col c+64,
// so a lane's uint32 load at byte row*256+4*l yields cols (l, l+64).
// convert2: both tables in one dispatch.
__global__ void convert2_kernel(const float* __restrict__ spot_x,
                                const float* __restrict__ user_x,
                                const float* __restrict__ isd_s,
                                const float* __restrict__ isd_u,
                                ushort* __restrict__ xbs, ushort* __restrict__ xbu,
                                int M, int N) {
    int idx = blockIdx.x * blockDim.x + threadIdx.x;
    if (idx >= ((M + N) << 6)) return;
    int row = idx >> 6, c = idx & 63;
    const float* x; float w; ushort* xb;
    if (row < M) { x = spot_x + ((size_t)row << 7); w = isd_s[row]; xb = xbs + ((size_t)row << 7); }
    else { row -= M; x = user_x + ((size_t)row << 7); w = isd_u[row]; xb = xbu + ((size_t)row << 7); }
    ushort2 o;
    o.x = f2bf(x[c] * w);
    o.y = f2bf(x[c + 64] * w);
    *reinterpret_cast<ushort2*>(xb + 2 * c) = o;
}

// Single-table convert (tier B).
__global__ void convert_kernel(const float* __restrict__ x, const float* __restrict__ isd,
                               ushort* __restrict__ xb, int n_rows) {
    int idx = blockIdx.x * blockDim.x + threadIdx.x;
    if (idx >= (n_rows << 6)) return;
    int row = idx >> 6, c = idx & 63;
    float w = isd[row];
    const float* xr = x + ((size_t)row << 7);
    ushort2 o;
    o.x = f2bf(xr[c] * w);
    o.y = f2bf(xr[c + 64] * w);
    *reinterpret_cast<ushort2*>(xb + ((size_t)row << 7) + 2 * c) = o;
}

// Both-direction partition in ONE kernel: reads each edge once, stages both
// (u<<16|s) and (s<<16|u) into LDS bucket-ordered, coalesced run flush.
__global__ __launch_bounds__(256) void part2_kernel(
        const int* __restrict__ u, const int* __restrict__ s, int E,
        int nbu, int nbs, int* __restrict__ gcu, int* __restrict__ gcs,
        uint32_t* __restrict__ outU, uint32_t* __restrict__ outS) {
    __shared__ int histU[MAXB], loffU[MAXB], gbaseU[MAXB], curU[MAXB];
    __shared__ int histS[MAXB], loffS[MAXB], gbaseS[MAXB], curS[MAXB];
    __shared__ int wsum[4];
    __shared__ uint32_t sbufU[PART_CHUNK];
    __shared__ uint32_t sbufS[PART_CHUNK];
    const int tid = threadIdx.x;
    const int lane = tid & 63;
    const int wid = tid >> 6;
    const int beg = blockIdx.x * PART_CHUNK;
    const int end = min(beg + PART_CHUNK, E);
    const int cnt_total = end - beg;
    for (int b = tid; b < nbu; b += 256) histU[b] = 0;
    for (int b = tid; b < nbs; b += 256) histS[b] = 0;
    __syncthreads();
    for (int i = beg + tid; i < end; i += 256) {
        atomicAdd(&histU[u[i] >> NPB_LOG2], 1);
        atomicAdd(&histS[s[i] >> NPB_LOG2], 1);
    }
    __syncthreads();
    // scan histU -> loffU, then histS -> loffS (3 buckets/thread each)
    for (int dir = 0; dir < 2; ++dir) {
        int nb = dir ? nbs : nbu;
        int* hist = dir ? histS : histU;
        int* loff = dir ? loffS : loffU;
        int b0 = tid * 3;
        int h0 = (b0 + 0 < nb) ? hist[b0 + 0] : 0;
        int h1 = (b0 + 1 < nb) ? hist[b0 + 1] : 0;
        int h2 = (b0 + 2 < nb) ? hist[b0 + 2] : 0;
        int tsum = h0 + h1 + h2;
        int x = tsum;
#pragma unroll
        for (int d = 1; d < 64; d <<= 1) {
            int t = __shfl_up(x, d);
            if (lane >= d) x += t;
        }
        if (lane == 63) wsum[wid] = x;
        __syncthreads();
        if (tid == 0) {
            int run = 0;
#pragma unroll
            for (int w = 0; w < 4; ++w) { int t = wsum[w]; wsum[w] = run; run += t; }
        }
        __syncthreads();
        int base = wsum[wid] + (x - tsum);
        if (b0 + 0 < nb) loff[b0 + 0] = base;
        if (b0 + 1 < nb) loff[b0 + 1] = base + h0;
        if (b0 + 2 < nb) loff[b0 + 2] = base + h0 + h1;
        __syncthreads();
    }
    for (int b = tid; b < nbu; b += 256) {
        curU[b] = loffU[b];
        int c = histU[b];
        gbaseU[b] = c > 0 ? atomicAdd(&gcu[b], c) : 0;
    }
    for (int b = tid; b < nbs; b += 256) {
        curS[b] = loffS[b];
        int c = histS[b];
        gbaseS[b] = c > 0 ? atomicAdd(&gcs[b], c) : 0;
    }
    __syncthreads();
    for (int i = beg + tid; i < end; i += 256) {
        int uu = u[i], ss = s[i];
        int lu = atomicAdd(&curU[uu >> NPB_LOG2], 1);
        sbufU[lu] = ((uint32_t)uu << 16) | (uint32_t)ss;
        int ls = atomicAdd(&curS[ss >> NPB_LOG2], 1);
        sbufS[ls] = ((uint32_t)ss << 16) | (uint32_t)uu;
    }
    __syncthreads();
    for (int k = tid; k < cnt_total; k += 256) {
        uint32_t p = sbufU[k];
        int b = (int)(p >> (16 + NPB_LOG2));
        outU[gbaseU[b] + (k - loffU[b])] = p;
        uint32_t q = sbufS[k];
        int b2 = (int)(q >> (16 + NPB_LOG2));
        outS[gbaseS[b2] + (k - loffS[b2])] = q;
    }
}

// Histogram-only pass over BOTH bucketed edge buffers: isd = rsqrt(deg).
__global__ __launch_bounds__(256) void bdeg2_kernel(
        const uint32_t* __restrict__ bufU, const uint32_t* __restrict__ bufS,
        const int* __restrict__ buoff, const int* __restrict__ bsoff, int nbu,
        float* __restrict__ isd_u, float* __restrict__ isd_s, int N, int M) {
    __shared__ int hist[NPB];
    const int tid = threadIdx.x;
    const int b = blockIdx.x;
    const uint32_t* buf; const int* boff; float* isd; int n_rows; int bb;
    if (b < nbu) { buf = bufU; boff = buoff; isd = isd_u; n_rows = N; bb = b; }
    else         { buf = bufS; boff = bsoff; isd = isd_s; n_rows = M; bb = b - nbu; }
    const int jbeg = boff[bb];
    const int cnt = boff[bb + 1] - jbeg;
    if (tid < NPB) hist[tid] = 0;
    __syncthreads();
    for (int k = tid; k < cnt; k += 256)
        atomicAdd(&hist[(buf[jbeg + k] >> 16) & (NPB - 1)], 1);
    __syncthreads();
    if (tid < NPB) {
        int node = (bb << NPB_LOG2) + tid;
        if (node < n_rows) {
            int h = hist[tid];
            isd[node] = h > 0 ? rsqrtf((float)h) : 0.f;
        }
    }
}

// Split-bucket fused sort+scan, one direction per launch.
// Block = (bucket = blockIdx.x / split, sub = blockIdx.x % split); sub-range
// of the bucket's edges. Single global read into registers -> LDS dst hist ->
// ushort counting sort -> dst-major register accumulate -> atomic flush
// (sub-blocks of a bucket share output rows). isd precomputed (bdeg2).
__global__ __launch_bounds__(512) void fscan3_kernel(
        const ushort* __restrict__ xb, const uint32_t* __restrict__ buf,
        const int* __restrict__ boff, const float* __restrict__ isd,
        float* __restrict__ out, int split) {
    __shared__ ushort srt[RCAP];
    __shared__ int hist[NPB];
    __shared__ int scur[NPB];
    const int tid = threadIdx.x;
    const int bucket = blockIdx.x / split;
    const int sub = blockIdx.x - bucket * split;
    const int jb = boff[bucket];
    const int cnt = boff[bucket + 1] - jb;
    if (cnt <= 0) return;
    const int sbeg = jb + (int)((long long)cnt * sub / split);
    const int send = jb + (int)((long long)cnt * (sub + 1) / split);
    const int scnt = send - sbeg;
    if (scnt <= 0) return;
    const int wid = tid >> 6, lane = tid & 63;
    const int rowbase = bucket << NPB_LOG2;

#define ROWX(sv) (*reinterpret_cast<const uint32_t*>( \
        xb + (((size_t)(sv)) << 7) + (lane << 1)))
#define UPX(rv) __uint_as_float((rv) << 16)
#define UPY(rv) __uint_as_float((rv) & 0xffff0000u)

    if (scnt <= RCAP) {
        if (tid < NPB) hist[tid] = 0;
        __syncthreads();
        uint32_t ereg[8];
#pragma unroll
        for (int k = 0; k < 8; ++k) {
            int idx = sbeg + (k << 9) + tid;
            if (idx < send) {
                ereg[k] = buf[idx];
                atomicAdd(&hist[(ereg[k] >> 16) & (NPB - 1)], 1);
            } else ereg[k] = 0u;
        }
        __syncthreads();
        if (tid < NPB) {   // wave 0: exclusive scan
            int h = hist[tid];
            int x = h;
#pragma unroll
            for (int d = 1; d < 64; d <<= 1) {
                int t = __shfl_up(x, d);
                if (tid >= d) x += t;
            }
            scur[tid] = x - h;
        }
        __syncthreads();
#pragma unroll
        for (int k = 0; k < 8; ++k) {
            int idx = sbeg + (k << 9) + tid;
            if (idx < send) {
                uint32_t p = ereg[k];
                int slot = atomicAdd(&scur[(p >> 16) & (NPB - 1)], 1);
                srt[slot] = (ushort)p;
            }
        }
        __syncthreads();
        // dst-major: wave w owns local dsts w, w+8, ...
        for (int ld = wid; ld < NPB; ld += 8) {
            const int deg = hist[ld];
            if (!deg) continue;
            const int off0 = scur[ld] - deg;      // scur is now end offset
            float ax = 0.f, ay = 0.f;
            int j = 0;
            if (deg >= 16) {
                ushort c0 = srt[off0+0], c1 = srt[off0+1], c2 = srt[off0+2], c3 = srt[off0+3],
                       c4 = srt[off0+4], c5 = srt[off0+5], c6 = srt[off0+6], c7 = srt[off0+7];
                uint32_t r0 = ROWX(c0), r1 = ROWX(c1), r2 = ROWX(c2), r3 = ROWX(c3),
                         r4 = ROWX(c4), r5 = ROWX(c5), r6 = ROWX(c6), r7 = ROWX(c7);
                for (j = 8; j + 8 <= deg; j += 8) {
                    const int q = off0 + j;
                    ushort n0 = srt[q+0], n1 = srt[q+1], n2 = srt[q+2], n3 = srt[q+3],
                           n4 = srt[q+4], n5 = srt[q+5], n6 = srt[q+6], n7 = srt[q+7];
                    uint32_t s0 = ROWX(n0), s1 = ROWX(n1), s2 = ROWX(n2), s3 = ROWX(n3),
                             s4 = ROWX(n4), s5 = ROWX(n5), s6 = ROWX(n6), s7 = ROWX(n7);
                    ax += ((UPX(r0) + UPX(r1)) + (UPX(r2) + UPX(r3)))
                        + ((UPX(r4) + UPX(r5)) + (UPX(r6) + UPX(r7)));
                    ay += ((UPY(r0) + UPY(r1)) + (UPY(r2) + UPY(r3)))
                        + ((UPY(r4) + UPY(r5)) + (UPY(r6) + UPY(r7)));
                    r0 = s0; r1 = s1; r2 = s2; r3 = s3;
                    r4 = s4; r5 = s5; r6 = s6; r7 = s7;
                }
                ax += ((UPX(r0) + UPX(r1)) + (UPX(r2) + UPX(r3)))
                    + ((UPX(r4) + UPX(r5)) + (UPX(r6) + UPX(r7)));
                ay += ((UPY(r0) + UPY(r1)) + (UPY(r2) + UPY(r3)))
                    + ((UPY(r4) + UPY(r5)) + (UPY(r6) + UPY(r7)));
            }
            for (; j < deg; ++j) {
                uint32_t r = ROWX(srt[off0 + j]);
                ax += UPX(r); ay += UPY(r);
            }
            const float w = isd[rowbase + ld];
            const size_t ro = ((size_t)(rowbase + ld)) << 7;
            unsafeAtomicAdd(out + ro + lane,      ax * w);
            unsafeAtomicAdd(out + ro + 64 + lane, ay * w);
        }
    } else {
        // oversize sub-block (statistically absent): unsorted run-scan.
        const int cs = (scnt + 7) >> 3;
        const int beg = sbeg + wid * cs;
        const int end = min(beg + cs, send);
        if (beg >= end) return;
        float ax = 0.f, ay = 0.f;
        int curd = (int)(buf[beg] >> 16);
        for (int k = beg; k < end; ++k) {
            uint32_t p = buf[k];
            int d_ = (int)(p >> 16);
            if (d_ != curd) {
                float w_ = isd[curd];
                unsafeAtomicAdd(out + ((size_t)curd << 7) + lane, ax * w_);
                unsafeAtomicAdd(out + ((size_t)curd << 7) + 64 + lane, ay * w_);
                ax = 0.f; ay = 0.f; curd = d_;
            }
            uint32_t r = ROWX((ushort)p);
            ax += UPX(r); ay += UPY(r);
        }
        float w_ = isd[curd];
        unsafeAtomicAdd(out + ((size_t)curd << 7) + lane, ax * w_);
        unsafeAtomicAdd(out + ((size_t)curd << 7) + 64 + lane, ay * w_);
    }
#undef UPY
#undef UPX
#undef ROWX
}

// ---- tier-B kernels (round-8 proven sequential path) ----------------------

__global__ __launch_bounds__(256) void bdeg_kernel(
        const uint32_t* __restrict__ buf, const int* __restrict__ boff,
        float* __restrict__ isd, int n_rows) {
    __shared__ int hist[NPB];
    const int tid = threadIdx.x;
    const int jbeg = boff[blockIdx.x];
    const int cnt = boff[blockIdx.x + 1] - jbeg;
    if (tid < NPB) hist[tid] = 0;
    __syncthreads();
    for (int k = tid; k < cnt; k += 256)
        atomicAdd(&hist[(buf[jbeg + k] >> 16) & (NPB - 1)], 1);
    __syncthreads();
    if (tid < NPB) {
        int node = (blockIdx.x << NPB_LOG2) + tid;
        if (node < n_rows) {
            int h = hist[tid];
            isd[node] = h > 0 ? rsqrtf((float)h) : 0.f;
        }
    }
}

__global__ __launch_bounds__(512) void fscan_kernel(
        const ushort* __restrict__ xb, const uint32_t* __restrict__ buf,
        const int* __restrict__ boff, float* __restrict__ isd_out,
        float* __restrict__ out, int n_rows) {
    __shared__ uint32_t sorted[SORT_CAP];
    __shared__ int hist[NPB];
    __shared__ int scur[NPB];
    __shared__ float isdl[NPB];
    const int tid = threadIdx.x;
    const int jbeg = boff[blockIdx.x];
    const int cnt = boff[blockIdx.x + 1] - jbeg;
    if (cnt <= 0) {
        if (tid < NPB) {
            int node = (blockIdx.x << NPB_LOG2) + tid;
            if (node < n_rows) isd_out[node] = 0.f;
        }
        return;
    }
    const bool fits = (cnt <= SORT_CAP);
    if (tid < NPB) hist[tid] = 0;
    __syncthreads();
    for (int k = tid; k < cnt; k += 512)
        atomicAdd(&hist[(buf[jbeg + k] >> 16) & (NPB - 1)], 1);
    __syncthreads();
    if (tid < NPB) {
        int h = hist[tid];
        int x = h;
#pragma unroll
        for (int d = 1; d < 64; d <<= 1) {
            int t = __shfl_up(x, d);
            if (tid >= d) x += t;
        }
        scur[tid] = x - h;
        float iv = h > 0 ? rsqrtf((float)h) : 0.f;
        isdl[tid] = iv;
        int node = (blockIdx.x << NPB_LOG2) + tid;
        if (node < n_rows) isd_out[node] = iv;
    }
    __syncthreads();
    if (fits) {
        for (int k = tid; k < cnt; k += 512) {
            uint32_t p = buf[jbeg + k];
            int slot = atomicAdd(&scur[(p >> 16) & (NPB - 1)], 1);
            sorted[slot] = p;
        }
    }
    __syncthreads();
    const int wid = tid >> 6, lane = tid & 63;
    const int cs = (cnt + 7) >> 3;
    const int beg = wid * cs;
    const int end = min(beg + cs, cnt);
    if (beg >= end) return;

#define QLD(i) (fits ? sorted[i] : buf[jbeg + (i)])
#define ROW(pv) (*reinterpret_cast<const uint32_t*>( \
        xb + (((size_t)((pv) & 0xffffu)) << 7) + (lane << 1)))
#define UPX(rv) __uint_as_float((rv) << 16)
#define UPY(rv) __uint_as_float((rv) & 0xffff0000u)
    float ax = 0.f, ay = 0.f;
    int curd = (int)(QLD(beg) >> 16);
    for (int k = beg; k < end; ++k) {
        uint32_t p = QLD(k);
        int d_ = (int)(p >> 16);
        if (d_ != curd) {
            float w_ = isdl[curd & (NPB - 1)];
            unsafeAtomicAdd(out + ((size_t)curd << 7) + lane, ax * w_);
            unsafeAtomicAdd(out + ((size_t)curd << 7) + 64 + lane, ay * w_);
            ax = 0.f; ay = 0.f; curd = d_;
        }
        uint32_t r = ROW(p);
        ax += UPX(r); ay += UPY(r);
    }
    float w_ = isdl[curd & (NPB - 1)];
    unsafeAtomicAdd(out + ((size_t)curd << 7) + lane, ax * w_);
    unsafeAtomicAdd(out + ((size_t)curd << 7) + 64 + lane, ay * w_);
#undef UPY
#undef UPX
#undef ROW
#undef QLD
}

// ---- minimal-ws fallback ---------------------------------------------------

__global__ void deg_kernel(const int* __restrict__ u, const int* __restrict__ s,
                           int E, int* __restrict__ udeg, int* __restrict__ sdeg) {
    int i = blockIdx.x * blockDim.x + threadIdx.x;
    if (i < E) {
        atomicAdd(&udeg[u[i]], 1);
        atomicAdd(&sdeg[s[i]], 1);
    }
}

__global__ void init_isd_kernel(const int* __restrict__ udeg, const int* __restrict__ sdeg,
                                float* __restrict__ isd_u, float* __restrict__ isd_s,
                                int n_user, int m_spot) {
    int i = blockIdx.x * blockDim.x + threadIdx.x;
    if (i < n_user) { int d = udeg[i]; isd_u[i] = d > 0 ? rsqrtf((float)d) : 0.f; }
    if (i < m_spot) { int d = sdeg[i]; isd_s[i] = d > 0 ? rsqrtf((float)d) : 0.f; }
}

__global__ __launch_bounds__(256) void scatter_kernel(const float* __restrict__ spot_x,
                                                      const float* __restrict__ user_x,
                                                      const int* __restrict__ u,
                                                      const int* __restrict__ s, int E,
                                                      const float* __restrict__ isd_u,
                                                      const float* __restrict__ isd_s,
                                                      float* __restrict__ spot_out,
                                                      float* __restrict__ user_out) {
    const int lane = threadIdx.x & 63;
    const int e = blockIdx.x * 4 + (threadIdx.x >> 6);
    if (e >= E) return;
    const int uu = u[e], ss = s[e];
    const float w = isd_u[uu] * isd_s[ss];
    const float2 sv = *reinterpret_cast<const float2*>(spot_x + (size_t)ss * 128 + lane * 2);
    const float2 uv = *reinterpret_cast<const float2*>(user_x + (size_t)uu * 128 + lane * 2);
    atomicAdd(&user_out[(size_t)uu * 128 + lane * 2 + 0], sv.x * w);
    atomicAdd(&user_out[(size_t)uu * 128 + lane * 2 + 1], sv.y * w);
    atomicAdd(&spot_out[(size_t)ss * 128 + lane * 2 + 0], uv.x * w);
    atomicAdd(&spot_out[(size_t)ss * 128 + lane * 2 + 1], uv.y * w);
}

static inline char* align256(char* p) {
    return (char*)(((uintptr_t)p + 255u) & ~(uintptr_t)255u);
}

extern "C" void kernel_launch(void* const* d_in, const int* in_sizes, int n_in,
                              void* d_out, int out_size, void* d_ws, size_t ws_size,
                              hipStream_t stream) {
    const float* spot_x = (const float*)d_in[0];
    const float* user_x = (const float*)d_in[1];
    const int*   edges  = (const int*)d_in[2];
    const int M = in_sizes[0] / 128;   // spots
    const int N = in_sizes[1] / 128;   // users
    const int E = in_sizes[2] / 2;
    const int* u = edges;        // user_spot[0]
    const int* s = edges + E;    // user_spot[1]
    float* spot_out = (float*)d_out;
    float* user_out = (float*)d_out + (size_t)M * 128;

    const int nbu = (N + NPB - 1) / NPB;
    const int nbs = (M + NPB - 1) / NPB;
    const int nm = (N > M) ? N : M;
    const int gpart = (E + PART_CHUNK - 1) / PART_CHUNK;

    // Common metadata layout (shared by tiers A and B).
    char* ws = (char*)d_ws;
    float*    isd_u = (float*)ws; ws = align256(ws + sizeof(float) * (size_t)N);
    float*    isd_s = (float*)ws; ws = align256(ws + sizeof(float) * (size_t)M);
    int*      bd    = (int*)ws;   ws = align256(ws + sizeof(int) * (size_t)(nbu + nbs));
    int*      buoff = (int*)ws;   ws = align256(ws + sizeof(int) * (size_t)(nbu + 1));
    int*      bsoff = (int*)ws;   ws = align256(ws + sizeof(int) * (size_t)(nbs + 1));
    int*      gcu   = (int*)ws;   ws = align256(ws + sizeof(int) * (size_t)nbu);
    int*      gcs   = (int*)ws;   ws = align256(ws + sizeof(int) * (size_t)nbs);
    uint32_t* bufU  = (uint32_t*)ws; ws = align256(ws + sizeof(uint32_t) * (size_t)E);
    uint32_t* bufS  = (uint32_t*)ws; ws = align256(ws + sizeof(uint32_t) * (size_t)E);
    ushort*   xbs   = (ushort*)ws;   // tier A: spot table (tier B: union slot)
    ushort*   xbu   = (ushort*)align256((char*)xbs + sizeof(ushort) * ((size_t)M * 128));
    size_t tierA_needed = (size_t)((char*)xbu - (char*)d_ws)
                        + sizeof(ushort) * ((size_t)N * 128);
    size_t tierB_needed = (size_t)((char*)xbs - (char*)d_ws)
                        + sizeof(ushort) * ((size_t)nm * 128);

    if (tierB_needed <= ws_size && nbu <= MAXB && nbs <= MAXB) {
        hipMemsetAsync(bd, 0, sizeof(int) * (size_t)(nbu + nbs), stream);
        hipMemsetAsync(d_out, 0, sizeof(float) * (size_t)out_size, stream);
        bhist_kernel<<<(E + BH_CHUNK - 1) / BH_CHUNK, 256, 0, stream>>>(
            u, s, E, nbu, nbs, bd);
        scan2_kernel<<<2, 1024, 0, stream>>>(bd, nbu, nbs, buoff, bsoff, gcu, gcs);
        part2_kernel<<<gpart, 256, 0, stream>>>(u, s, E, nbu, nbs, gcu, gcs, bufU, bufS);
        if (tierA_needed <= ws_size) {
            // ---- tier A: split-block per-direction fscan3 ----------------
            bdeg2_kernel<<<nbu + nbs, 256, 0, stream>>>(
                bufU, bufS, buoff, bsoff, nbu, isd_u, isd_s, N, M);
            convert2_kernel<<<(((M + N) << 6) + 255) / 256, 256, 0, stream>>>(
                spot_x, user_x, isd_s, isd_u, xbs, xbu, M, N);
            int splitU = 2048 / nbu; if (splitU < 1) splitU = 1; if (splitU > 16) splitU = 16;
            int splitS = 2048 / nbs; if (splitS < 1) splitS = 1; if (splitS > 16) splitS = 16;
            fscan3_kernel<<<nbu * splitU, 512, 0, stream>>>(
                xbs, bufU, buoff, isd_u, user_out, splitU);
            fscan3_kernel<<<nbs * splitS, 512, 0, stream>>>(
                xbu, bufS, bsoff, isd_s, spot_out, splitS);
        } else {
            // ---- tier B: round-8 proven sequential path (union table) ----
            ushort* xb = xbs;
            bdeg_kernel<<<nbs, 256, 0, stream>>>(bufS, bsoff, isd_s, M);
            convert_kernel<<<((M << 6) + 255) / 256, 256, 0, stream>>>(spot_x, isd_s, xb, M);
            fscan_kernel<<<nbu, 512, 0, stream>>>(xb, bufU, buoff, isd_u, user_out, N);
            convert_kernel<<<((N << 6) + 255) / 256, 256, 0, stream>>>(user_x, isd_u, xb, N);
            fscan_kernel<<<nbs, 512, 0, stream>>>(xb, bufS, bsoff, isd_s, spot_out, M);
        }
        return;
    }

    // ---- minimal-ws fallback: degree + atomic scatter ----------------------
    {
        char* w2 = (char*)d_ws;
        int*   udeg2  = (int*)w2;   w2 += sizeof(int) * (size_t)N;
        int*   sdeg2  = (int*)w2;   w2 += sizeof(int) * (size_t)M;
        float* isd_u2 = (float*)w2; w2 += sizeof(float) * (size_t)N;
        float* isd_s2 = (float*)w2; w2 += sizeof(float) * (size_t)M;
        if ((size_t)(w2 - (char*)d_ws) <= ws_size) {
            hipMemsetAsync(udeg2, 0, sizeof(int) * (size_t)(N + M), stream);
            deg_kernel<<<(E + 255) / 256, 256, 0, stream>>>(u, s, E, udeg2, sdeg2);
            init_isd_kernel<<<(nm + 255) / 256, 256, 0, stream>>>(
                udeg2, sdeg2, isd_u2, isd_s2, N, M);
            hipMemsetAsync(d_out, 0, sizeof(float) * (size_t)out_size, stream);
            scatter_kernel<<<((size_t)E + 3) / 4, 256, 0, stream>>>(
                spot_x, user_x, u, s, E, isd_u2, isd_s2, spot_out, user_out);
        }
    }
}

// Round 11
// 238.316 us; speedup vs baseline: 1.2320x; 1.2320x over previous
//
#include <hip/hip_runtime.h>
#include <stdint.h>

// ---------------------------------------------------------------------------
// UserSpotConv: bipartite GCN aggregation.
//   user_out[u] = isd_u[u] * sum_{e: u_e=u} spot_x[s_e] * isd_s[s_e]
//   spot_out[s] = isd_s[s] * sum_{e: s_e=s} user_x[u_e] * isd_u[u_e]
// Round 11 (consolidation): r8/r9/r10 all lost to the plain cscan gather
// (60us/dir @ ~166MB L2-miss traffic = the floor for this decomposition).
// Keep r7's proven bsort3+cscan; apply only the orthogonal proven trims:
//   part2   : both directions partitioned in ONE kernel (edges read once)
//   bsort3b : both directions' bucket sorts in ONE dispatch (writes isd)
//   convert2: both bf16 tables in ONE dispatch
// Pipeline: memset -> bhist -> scan2 -> part2 -> bsort3b -> convert2 ->
//           cscan_u -> cscan_s   (8 dispatches)
// ---------------------------------------------------------------------------

#define NPB_LOG2 6
#define NPB 64             // destination nodes per bucket
#define MAXB 768           // max buckets per direction
#define PART_CHUNK 2048    // edges per block in part2_kernel
#define BH_CHUNK 16384     // edges per block in bhist_kernel
#define SORT_CAP 8192      // max edges per bucket for bsort staging
#define CSCAN_CH 256       // edges per wave in cscan

__device__ __forceinline__ ushort f2bf(float f) {
    uint32_t u = __float_as_uint(f);
    return (ushort)((u + 0x7fffu + ((u >> 16) & 1u)) >> 16);  // RNE
}

// Bucket-level histogram for BOTH directions in one pass.
__global__ __launch_bounds__(256) void bhist_kernel(
        const int* __restrict__ u, const int* __restrict__ s, int E,
        int nbu, int nbs, int* __restrict__ bd) {
    __shared__ int hist[2 * MAXB];
    const int tid = threadIdx.x;
    const int nb = nbu + nbs;
    const int beg = blockIdx.x * BH_CHUNK;
    const int end = min(beg + BH_CHUNK, E);
    for (int b = tid; b < nb; b += 256) hist[b] = 0;
    __syncthreads();
    for (int i = beg + tid; i < end; i += 256) {
        atomicAdd(&hist[u[i] >> NPB_LOG2], 1);
        atomicAdd(&hist[nbu + (s[i] >> NPB_LOG2)], 1);
    }
    __syncthreads();
    for (int b = tid; b < nb; b += 256) {
        int h = hist[b];
        if (h) atomicAdd(&bd[b], h);
    }
}

// Fused dual exclusive scan (block 0: u-buckets, block 1: s-buckets) that
// also initializes the part2 global cursors. n <= 1024 (MAXB=768).
__global__ __launch_bounds__(1024) void scan2_kernel(
        const int* __restrict__ bd, int nbu, int nbs,
        int* __restrict__ buoff, int* __restrict__ bsoff,
        int* __restrict__ gcu, int* __restrict__ gcs) {
    __shared__ int wsums[16];
    __shared__ int total;
    const int tid = threadIdx.x, lane = tid & 63, wid = tid >> 6;
    const int n   = blockIdx.x ? nbs : nbu;
    const int* in = blockIdx.x ? (bd + nbu) : bd;
    int* out = blockIdx.x ? bsoff : buoff;
    int* gc  = blockIdx.x ? gcs   : gcu;
    int v = (tid < n) ? in[tid] : 0;
    int x = v;
#pragma unroll
    for (int d = 1; d < 64; d <<= 1) {
        int t = __shfl_up(x, d);
        if (lane >= d) x += t;
    }
    if (lane == 63) wsums[wid] = x;
    __syncthreads();
    if (tid == 0) {
        int run = 0;
#pragma unroll
        for (int w = 0; w < 16; ++w) { int t = wsums[w]; wsums[w] = run; run += t; }
        total = run;
    }
    __syncthreads();
    int excl = wsums[wid] + (x - v);
    if (tid < n) { out[tid] = excl; gc[tid] = excl; }
    if (tid == 0) out[n] = total;
}

// xb row layout is PERMUTED: slot 2c holds col c, slot 2c+1 holds col c+64,
// so a lane's uint32 load at byte row*256+4*l yields cols (l, l+64).
// convert2: both tables in one dispatch.
__global__ void convert2_kernel(const float* __restrict__ spot_x,
                                const float* __restrict__ user_x,
                                const float* __restrict__ isd_s,
                                const float* __restrict__ isd_u,
                                ushort* __restrict__ xbs, ushort* __restrict__ xbu,
                                int M, int N) {
    int idx = blockIdx.x * blockDim.x + threadIdx.x;
    if (idx >= ((M + N) << 6)) return;
    int row = idx >> 6, c = idx & 63;
    const float* x; float w; ushort* xb;
    if (row < M) { x = spot_x + ((size_t)row << 7); w = isd_s[row]; xb = xbs + ((size_t)row << 7); }
    else { row -= M; x = user_x + ((size_t)row << 7); w = isd_u[row]; xb = xbu + ((size_t)row << 7); }
    ushort2 o;
    o.x = f2bf(x[c] * w);
    o.y = f2bf(x[c + 64] * w);
    *reinterpret_cast<ushort2*>(xb + 2 * c) = o;
}

// Single-table convert (tier B).
__global__ void convert_kernel(const float* __restrict__ x, const float* __restrict__ isd,
                               ushort* __restrict__ xb, int n_rows) {
    int idx = blockIdx.x * blockDim.x + threadIdx.x;
    if (idx >= (n_rows << 6)) return;
    int row = idx >> 6, c = idx & 63;
    float w = isd[row];
    const float* xr = x + ((size_t)row << 7);
    ushort2 o;
    o.x = f2bf(xr[c] * w);
    o.y = f2bf(xr[c + 64] * w);
    *reinterpret_cast<ushort2*>(xb + ((size_t)row << 7) + 2 * c) = o;
}

// Both-direction partition in ONE kernel: reads each edge once, stages both
// (u<<16|s) and (s<<16|u) into LDS bucket-ordered, coalesced run flush.
__global__ __launch_bounds__(256) void part2_kernel(
        const int* __restrict__ u, const int* __restrict__ s, int E,
        int nbu, int nbs, int* __restrict__ gcu, int* __restrict__ gcs,
        uint32_t* __restrict__ outU, uint32_t* __restrict__ outS) {
    __shared__ int histU[MAXB], loffU[MAXB], gbaseU[MAXB], curU[MAXB];
    __shared__ int histS[MAXB], loffS[MAXB], gbaseS[MAXB], curS[MAXB];
    __shared__ int wsum[4];
    __shared__ uint32_t sbufU[PART_CHUNK];
    __shared__ uint32_t sbufS[PART_CHUNK];
    const int tid = threadIdx.x;
    const int lane = tid & 63;
    const int wid = tid >> 6;
    const int beg = blockIdx.x * PART_CHUNK;
    const int end = min(beg + PART_CHUNK, E);
    const int cnt_total = end - beg;
    for (int b = tid; b < nbu; b += 256) histU[b] = 0;
    for (int b = tid; b < nbs; b += 256) histS[b] = 0;
    __syncthreads();
    for (int i = beg + tid; i < end; i += 256) {
        atomicAdd(&histU[u[i] >> NPB_LOG2], 1);
        atomicAdd(&histS[s[i] >> NPB_LOG2], 1);
    }
    __syncthreads();
    for (int dir = 0; dir < 2; ++dir) {
        int nb = dir ? nbs : nbu;
        int* hist = dir ? histS : histU;
        int* loff = dir ? loffS : loffU;
        int b0 = tid * 3;
        int h0 = (b0 + 0 < nb) ? hist[b0 + 0] : 0;
        int h1 = (b0 + 1 < nb) ? hist[b0 + 1] : 0;
        int h2 = (b0 + 2 < nb) ? hist[b0 + 2] : 0;
        int tsum = h0 + h1 + h2;
        int x = tsum;
#pragma unroll
        for (int d = 1; d < 64; d <<= 1) {
            int t = __shfl_up(x, d);
            if (lane >= d) x += t;
        }
        if (lane == 63) wsum[wid] = x;
        __syncthreads();
        if (tid == 0) {
            int run = 0;
#pragma unroll
            for (int w = 0; w < 4; ++w) { int t = wsum[w]; wsum[w] = run; run += t; }
        }
        __syncthreads();
        int base = wsum[wid] + (x - tsum);
        if (b0 + 0 < nb) loff[b0 + 0] = base;
        if (b0 + 1 < nb) loff[b0 + 1] = base + h0;
        if (b0 + 2 < nb) loff[b0 + 2] = base + h0 + h1;
        __syncthreads();
    }
    for (int b = tid; b < nbu; b += 256) {
        curU[b] = loffU[b];
        int c = histU[b];
        gbaseU[b] = c > 0 ? atomicAdd(&gcu[b], c) : 0;
    }
    for (int b = tid; b < nbs; b += 256) {
        curS[b] = loffS[b];
        int c = histS[b];
        gbaseS[b] = c > 0 ? atomicAdd(&gcs[b], c) : 0;
    }
    __syncthreads();
    for (int i = beg + tid; i < end; i += 256) {
        int uu = u[i], ss = s[i];
        int lu = atomicAdd(&curU[uu >> NPB_LOG2], 1);
        sbufU[lu] = ((uint32_t)uu << 16) | (uint32_t)ss;
        int ls = atomicAdd(&curS[ss >> NPB_LOG2], 1);
        sbufS[ls] = ((uint32_t)ss << 16) | (uint32_t)uu;
    }
    __syncthreads();
    for (int k = tid; k < cnt_total; k += 256) {
        uint32_t p = sbufU[k];
        int b = (int)(p >> (16 + NPB_LOG2));
        outU[gbaseU[b] + (k - loffU[b])] = p;
        uint32_t q = sbufS[k];
        int b2 = (int)(q >> (16 + NPB_LOG2));
        outS[gbaseS[b2] + (k - loffS[b2])] = q;
    }
}

// Combined-direction per-bucket counting sort by dst, in place (LDS-staged),
// AND write isd = rsqrt(degree) from the self-computed histogram. Blocks
// [0, nbu) handle bufU; [nbu, nbu+nbs) handle bufS. Sort is perf-only.
__global__ __launch_bounds__(256) void bsort3b_kernel(
        uint32_t* __restrict__ bufU, uint32_t* __restrict__ bufS,
        const int* __restrict__ buoff, const int* __restrict__ bsoff, int nbu,
        float* __restrict__ isd_u, float* __restrict__ isd_s, int N, int M) {
    __shared__ uint32_t stage[SORT_CAP];
    __shared__ int hist[NPB];
    __shared__ int cur[NPB];
    const int tid = threadIdx.x;
    const int b = blockIdx.x;
    uint32_t* buf; const int* boff; float* isd; int n_rows; int bb;
    if (b < nbu) { buf = bufU; boff = buoff; isd = isd_u; n_rows = N; bb = b; }
    else         { buf = bufS; boff = bsoff; isd = isd_s; n_rows = M; bb = b - nbu; }
    const int jbeg = boff[bb];
    const int cnt = boff[bb + 1] - jbeg;
    const bool fits = (cnt <= SORT_CAP);   // sort perf-only; isd always written
    if (tid < NPB) hist[tid] = 0;
    __syncthreads();
    for (int k = tid; k < cnt; k += 256) {
        uint32_t p = buf[jbeg + k];
        if (fits) stage[k] = p;
        atomicAdd(&hist[(p >> 16) & (NPB - 1)], 1);
    }
    __syncthreads();   // drains global reads before in-place overwrite
    if (tid < NPB) {   // wave 0: 64-wide exclusive scan via shfl + isd write
        int h = hist[tid];
        int x = h;
#pragma unroll
        for (int d = 1; d < 64; d <<= 1) {
            int t = __shfl_up(x, d);
            if (tid >= d) x += t;
        }
        cur[tid] = x - h;
        int node = (bb << NPB_LOG2) + tid;
        if (node < n_rows) isd[node] = h > 0 ? rsqrtf((float)h) : 0.f;
    }
    __syncthreads();
    if (fits) {
        for (int k = tid; k < cnt; k += 256) {
            uint32_t p = stage[k];
            int slot = atomicAdd(&cur[(p >> 16) & (NPB - 1)], 1);
            buf[jbeg + slot] = p;
        }
    }
}

// Wave per CSCAN_CH consecutive dst-sorted edges; register accumulate,
// flush on dst change via native f32 atomic. (Proven 60us/dir — the
// fetch floor of this decomposition; r8/r9/r10 restructures all lost.)
__global__ __launch_bounds__(256) void cscan_kernel(
        const ushort* __restrict__ xb, const uint32_t* __restrict__ packed, int E,
        const float* __restrict__ isd, float* __restrict__ out) {
    const int lane = threadIdx.x & 63;
    const int wave = (blockIdx.x << 2) + (threadIdx.x >> 6);
    const int base = wave * CSCAN_CH;
    if (base >= E) return;
    const int n = min(CSCAN_CH, E - base);
    const uint32_t* pp = packed + base;
    float ax = 0.f, ay = 0.f;
    int cur = (int)(pp[0] >> 16);

#define ROW(pv) (*reinterpret_cast<const uint32_t*>( \
        xb + (((size_t)((pv) & 0xffffu)) << 7) + (lane << 1)))
#define UPX(rv) __uint_as_float((rv) << 16)
#define UPY(rv) __uint_as_float((rv) & 0xffff0000u)
#define FLUSH() do { float w_ = isd[cur];                                  \
        unsafeAtomicAdd(out + ((size_t)cur << 7) + lane, ax * w_);         \
        unsafeAtomicAdd(out + ((size_t)cur << 7) + 64 + lane, ay * w_);    \
        ax = 0.f; ay = 0.f; } while (0)
#define PROC(pv, rv) do { int d_ = (int)((pv) >> 16);                      \
        if (d_ != cur) { FLUSH(); cur = d_; }                              \
        ax += UPX(rv); ay += UPY(rv); } while (0)
#define GRP8(Aa, Ab, r0, r1, r2, r3, r4, r5, r6, r7) do {                  \
    if ((((Aa.x ^ Ab.w) >> 16) == 0) && ((int)(Aa.x >> 16) == cur)) {      \
        float sx = ((UPX(r0) + UPX(r1)) + (UPX(r2) + UPX(r3)))             \
                 + ((UPX(r4) + UPX(r5)) + (UPX(r6) + UPX(r7)));            \
        float sy = ((UPY(r0) + UPY(r1)) + (UPY(r2) + UPY(r3)))             \
                 + ((UPY(r4) + UPY(r5)) + (UPY(r6) + UPY(r7)));            \
        ax += sx; ay += sy;                                                \
    } else {                                                               \
        PROC(Aa.x, r0); PROC(Aa.y, r1); PROC(Aa.z, r2); PROC(Aa.w, r3);    \
        PROC(Ab.x, r4); PROC(Ab.y, r5); PROC(Ab.z, r6); PROC(Ab.w, r7);    \
    } } while (0)

    int k = 0;
    if (n >= 24) {
        uint4 P0a = *(const uint4*)(pp + 0),  P0b = *(const uint4*)(pp + 4);
        uint4 P1a = *(const uint4*)(pp + 8),  P1b = *(const uint4*)(pp + 12);
        uint32_t a0 = ROW(P0a.x), a1 = ROW(P0a.y), a2 = ROW(P0a.z), a3 = ROW(P0a.w),
                 a4 = ROW(P0b.x), a5 = ROW(P0b.y), a6 = ROW(P0b.z), a7 = ROW(P0b.w);
        uint4 P2a = *(const uint4*)(pp + 16), P2b = *(const uint4*)(pp + 20);
        uint32_t b0 = ROW(P1a.x), b1 = ROW(P1a.y), b2 = ROW(P1a.z), b3 = ROW(P1a.w),
                 b4 = ROW(P1b.x), b5 = ROW(P1b.y), b6 = ROW(P1b.z), b7 = ROW(P1b.w);
        for (k = 24; k + 8 <= n; k += 8) {
            uint4 P3a = *(const uint4*)(pp + k), P3b = *(const uint4*)(pp + k + 4);
            uint32_t c0 = ROW(P2a.x), c1 = ROW(P2a.y), c2 = ROW(P2a.z), c3 = ROW(P2a.w),
                     c4 = ROW(P2b.x), c5 = ROW(P2b.y), c6 = ROW(P2b.z), c7 = ROW(P2b.w);
            GRP8(P0a, P0b, a0, a1, a2, a3, a4, a5, a6, a7);
            P0a = P1a; P0b = P1b; P1a = P2a; P1b = P2b; P2a = P3a; P2b = P3b;
            a0 = b0; a1 = b1; a2 = b2; a3 = b3; a4 = b4; a5 = b5; a6 = b6; a7 = b7;
            b0 = c0; b1 = c1; b2 = c2; b3 = c3; b4 = c4; b5 = c5; b6 = c6; b7 = c7;
        }
        uint32_t c0 = ROW(P2a.x), c1 = ROW(P2a.y), c2 = ROW(P2a.z), c3 = ROW(P2a.w),
                 c4 = ROW(P2b.x), c5 = ROW(P2b.y), c6 = ROW(P2b.z), c7 = ROW(P2b.w);
        GRP8(P0a, P0b, a0, a1, a2, a3, a4, a5, a6, a7);
        GRP8(P1a, P1b, b0, b1, b2, b3, b4, b5, b6, b7);
        GRP8(P2a, P2b, c0, c1, c2, c3, c4, c5, c6, c7);
    }
    for (; k < n; ++k) {
        uint32_t p = pp[k];
        uint32_t r = ROW(p);
        PROC(p, r);
    }
    FLUSH();
#undef GRP8
#undef PROC
#undef FLUSH
#undef UPY
#undef UPX
#undef ROW
}

// ---- minimal-ws fallback ---------------------------------------------------

__global__ void deg_kernel(const int* __restrict__ u, const int* __restrict__ s,
                           int E, int* __restrict__ udeg, int* __restrict__ sdeg) {
    int i = blockIdx.x * blockDim.x + threadIdx.x;
    if (i < E) {
        atomicAdd(&udeg[u[i]], 1);
        atomicAdd(&sdeg[s[i]], 1);
    }
}

__global__ void init_isd_kernel(const int* __restrict__ udeg, const int* __restrict__ sdeg,
                                float* __restrict__ isd_u, float* __restrict__ isd_s,
                                int n_user, int m_spot) {
    int i = blockIdx.x * blockDim.x + threadIdx.x;
    if (i < n_user) { int d = udeg[i]; isd_u[i] = d > 0 ? rsqrtf((float)d) : 0.f; }
    if (i < m_spot) { int d = sdeg[i]; isd_s[i] = d > 0 ? rsqrtf((float)d) : 0.f; }
}

__global__ __launch_bounds__(256) void scatter_kernel(const float* __restrict__ spot_x,
                                                      const float* __restrict__ user_x,
                                                      const int* __restrict__ u,
                                                      const int* __restrict__ s, int E,
                                                      const float* __restrict__ isd_u,
                                                      const float* __restrict__ isd_s,
                                                      float* __restrict__ spot_out,
                                                      float* __restrict__ user_out) {
    const int lane = threadIdx.x & 63;
    const int e = blockIdx.x * 4 + (threadIdx.x >> 6);
    if (e >= E) return;
    const int uu = u[e], ss = s[e];
    const float w = isd_u[uu] * isd_s[ss];
    const float2 sv = *reinterpret_cast<const float2*>(spot_x + (size_t)ss * 128 + lane * 2);
    const float2 uv = *reinterpret_cast<const float2*>(user_x + (size_t)uu * 128 + lane * 2);
    atomicAdd(&user_out[(size_t)uu * 128 + lane * 2 + 0], sv.x * w);
    atomicAdd(&user_out[(size_t)uu * 128 + lane * 2 + 1], sv.y * w);
    atomicAdd(&spot_out[(size_t)ss * 128 + lane * 2 + 0], uv.x * w);
    atomicAdd(&spot_out[(size_t)ss * 128 + lane * 2 + 1], uv.y * w);
}

static inline char* align256(char* p) {
    return (char*)(((uintptr_t)p + 255u) & ~(uintptr_t)255u);
}

extern "C" void kernel_launch(void* const* d_in, const int* in_sizes, int n_in,
                              void* d_out, int out_size, void* d_ws, size_t ws_size,
                              hipStream_t stream) {
    const float* spot_x = (const float*)d_in[0];
    const float* user_x = (const float*)d_in[1];
    const int*   edges  = (const int*)d_in[2];
    const int M = in_sizes[0] / 128;   // spots
    const int N = in_sizes[1] / 128;   // users
    const int E = in_sizes[2] / 2;
    const int* u = edges;        // user_spot[0]
    const int* s = edges + E;    // user_spot[1]
    float* spot_out = (float*)d_out;
    float* user_out = (float*)d_out + (size_t)M * 128;

    const int nbu = (N + NPB - 1) / NPB;
    const int nbs = (M + NPB - 1) / NPB;
    const int nm = (N > M) ? N : M;
    const int gpart = (E + PART_CHUNK - 1) / PART_CHUNK;
    const int gscan = ((E + CSCAN_CH - 1) / CSCAN_CH + 3) / 4;

    // Common metadata layout (shared by tiers A and B).
    char* ws = (char*)d_ws;
    float*    isd_u = (float*)ws; ws = align256(ws + sizeof(float) * (size_t)N);
    float*    isd_s = (float*)ws; ws = align256(ws + sizeof(float) * (size_t)M);
    int*      bd    = (int*)ws;   ws = align256(ws + sizeof(int) * (size_t)(nbu + nbs));
    int*      buoff = (int*)ws;   ws = align256(ws + sizeof(int) * (size_t)(nbu + 1));
    int*      bsoff = (int*)ws;   ws = align256(ws + sizeof(int) * (size_t)(nbs + 1));
    int*      gcu   = (int*)ws;   ws = align256(ws + sizeof(int) * (size_t)nbu);
    int*      gcs   = (int*)ws;   ws = align256(ws + sizeof(int) * (size_t)nbs);
    uint32_t* bufU  = (uint32_t*)ws; ws = align256(ws + sizeof(uint32_t) * (size_t)E);
    uint32_t* bufS  = (uint32_t*)ws; ws = align256(ws + sizeof(uint32_t) * (size_t)E);
    ushort*   xbs   = (ushort*)ws;   // tier A: spot table (tier B: union slot)
    ushort*   xbu   = (ushort*)align256((char*)xbs + sizeof(ushort) * ((size_t)M * 128));
    size_t tierA_needed = (size_t)((char*)xbu - (char*)d_ws)
                        + sizeof(ushort) * ((size_t)N * 128);
    size_t tierB_needed = (size_t)((char*)xbs - (char*)d_ws)
                        + sizeof(ushort) * ((size_t)nm * 128);

    if (tierB_needed <= ws_size && nbu <= MAXB && nbs <= MAXB) {
        hipMemsetAsync(bd, 0, sizeof(int) * (size_t)(nbu + nbs), stream);
        hipMemsetAsync(d_out, 0, sizeof(float) * (size_t)out_size, stream);
        bhist_kernel<<<(E + BH_CHUNK - 1) / BH_CHUNK, 256, 0, stream>>>(
            u, s, E, nbu, nbs, bd);
        scan2_kernel<<<2, 1024, 0, stream>>>(bd, nbu, nbs, buoff, bsoff, gcu, gcs);
        part2_kernel<<<gpart, 256, 0, stream>>>(u, s, E, nbu, nbs, gcu, gcs, bufU, bufS);
        bsort3b_kernel<<<nbu + nbs, 256, 0, stream>>>(
            bufU, bufS, buoff, bsoff, nbu, isd_u, isd_s, N, M);
        if (tierA_needed <= ws_size) {
            // ---- tier A: both tables resident, sequential cscans ---------
            convert2_kernel<<<(((M + N) << 6) + 255) / 256, 256, 0, stream>>>(
                spot_x, user_x, isd_s, isd_u, xbs, xbu, M, N);
            cscan_kernel<<<gscan, 256, 0, stream>>>(xbs, bufU, E, isd_u, user_out);
            cscan_kernel<<<gscan, 256, 0, stream>>>(xbu, bufS, E, isd_s, spot_out);
        } else {
            // ---- tier B: union table slot, sequential --------------------
            ushort* xb = xbs;
            convert_kernel<<<((M << 6) + 255) / 256, 256, 0, stream>>>(spot_x, isd_s, xb, M);
            cscan_kernel<<<gscan, 256, 0, stream>>>(xb, bufU, E, isd_u, user_out);
            convert_kernel<<<((N << 6) + 255) / 256, 256, 0, stream>>>(user_x, isd_u, xb, N);
            cscan_kernel<<<gscan, 256, 0, stream>>>(xb, bufS, E, isd_s, spot_out);
        }
        return;
    }

    // ---- minimal-ws fallback: degree + atomic scatter ----------------------
    {
        char* w2 = (char*)d_ws;
        int*   udeg2  = (int*)w2;   w2 += sizeof(int) * (size_t)N;
        int*   sdeg2  = (int*)w2;   w2 += sizeof(int) * (size_t)M;
        float* isd_u2 = (float*)w2; w2 += sizeof(float) * (size_t)N;
        float* isd_s2 = (float*)w2; w2 += sizeof(float) * (size_t)M;
        if ((size_t)(w2 - (char*)d_ws) <= ws_size) {
            hipMemsetAsync(udeg2, 0, sizeof(int) * (size_t)(N + M), stream);
            deg_kernel<<<(E + 255) / 256, 256, 0, stream>>>(u, s, E, udeg2, sdeg2);
            init_isd_kernel<<<(nm + 255) / 256, 256, 0, stream>>>(
                udeg2, sdeg2, isd_u2, isd_s2, N, M);
            hipMemsetAsync(d_out, 0, sizeof(float) * (size_t)out_size, stream);
            scatter_kernel<<<((size_t)E + 3) / 4, 256, 0, stream>>>(
                spot_x, user_x, u, s, E, isd_u2, isd_s2, spot_out, user_out);
        }
    }
}